// Round 1
// baseline (1105.672 us; speedup 1.0000x reference)
//
#include <hip/hip_runtime.h>
#include <stdint.h>

static constexpr int N_ = 8192, C_ = 16, SI_ = 128, VI_ = 32, R_ = 32, H_ = 4, CAT_ = 160;

// ---- ws layout (float offsets) ----
static constexpr long SZ_LOGITS = (long)N_*C_*R_;              // 4194304
static constexpr long OFF_LOGITS = 0;
static constexpr long OFF_PM  = OFF_LOGITS + SZ_LOGITS;
static constexpr long SZ_PM   = 32L*C_*R_;                     // 16384
static constexpr long OFF_PS  = OFF_PM + SZ_PM;
static constexpr long OFF_M   = OFF_PS + SZ_PM;
static constexpr long OFF_INV = OFF_M + C_*R_;
static constexpr long OFF_SGL = OFF_INV + C_*R_;
static constexpr long SZ_SGL  = (long)R_*C_*SI_;               // 65536
static constexpr long OFF_VGL = OFF_SGL + SZ_SGL;
static constexpr long SZ_VGL  = (long)R_*C_*VI_*3;             // 49152
static constexpr long OFF_KS  = OFF_VGL + SZ_VGL;              // ks_t[c][h][j][r]
static constexpr long SZ_KS   = (long)C_*H_*32*32;
static constexpr long OFF_KV  = OFF_KS + SZ_KS;                // kv_t[c][h][od][r]
static constexpr long SZ_KV   = (long)C_*H_*24*32;
static constexpr long OFF_VSC = OFF_KV + SZ_KV;                // vs_c[c][h][r][j]
static constexpr long OFF_VVC = OFF_VSC + SZ_KS;               // vv_c[c][h][r][od]
static constexpr long OFF_W   = OFF_VVC + SZ_KV;
// weight sub-offsets (floats/uints) relative to OFF_W
static constexpr long W_WPWH=0, W_WPWS=1024, W_QWH=6144, W_QWV=7168, W_QWSV=8192,
  W_QWSB=12288 /*uint[64][164] bf16-pairs*/, W_KWH=22784, W_KWS=23808, W_KWV=44288,
  W_KWSV=45312, W_VWH=49408, W_VWS=50432, W_VWV=70912, W_VWSV=71936, W_END=76032;

__device__ __forceinline__ uint32_t f2bf(float f){
  uint32_t u = __float_as_uint(f);
  return (u + 0x7FFFu + ((u>>16)&1u)) >> 16;
}

// ---------------- k0: transpose weights into ws ----------------
__global__ void k0_transpose(const float* __restrict__ wpwh, const float* __restrict__ wpws,
    const float* __restrict__ qwh, const float* __restrict__ qws, const float* __restrict__ qwv,
    const float* __restrict__ qwsv, const float* __restrict__ kwh, const float* __restrict__ kws,
    const float* __restrict__ kwv, const float* __restrict__ kwsv, const float* __restrict__ vwh,
    const float* __restrict__ vws, const float* __restrict__ vwv, const float* __restrict__ vwsv,
    float* __restrict__ ws){
  int job = blockIdx.x; int t = threadIdx.x;
  float* W = ws + OFF_W;
  auto tr = [&](const float* src, float* dst, int O, int J){
    for(int idx=t; idx<O*J; idx+=blockDim.x){ int o=idx/J, j=idx-o*J; dst[j*O+o]=src[idx]; }
  };
  switch(job){
    case 0: tr(wpwh, W+W_WPWH, 32,32); break;        // [i][h]
    case 1: tr(wpws, W+W_WPWS, 32,160); break;       // [j][a]
    case 2: tr(qwh, W+W_QWH, 32,32); break;
    case 3: tr(qwv, W+W_QWV, 32,32); break;          // [h][o]
    case 4: tr(qwsv, W+W_QWSV, 32,128); break;       // [o][g]
    case 5: { uint32_t* dst=(uint32_t*)(W+W_QWSB);
      for(int idx=t; idx<64*160; idx+=blockDim.x){ int l=idx/160, j=idx-l*160;
        uint32_t lo=f2bf(qws[(2*l)*160+j]), hi=f2bf(qws[(2*l+1)*160+j]);
        dst[l*164+j] = lo | (hi<<16); } } break;
    case 6: tr(kwh, W+W_KWH,32,32); break;
    case 7: tr(kws, W+W_KWS,128,160); break;         // [j][o]
    case 8: tr(kwv, W+W_KWV,32,32); break;
    case 9: tr(kwsv, W+W_KWSV,32,128); break;
    case 10: tr(vwh, W+W_VWH,32,32); break;
    case 11: tr(vws, W+W_VWS,128,160); break;
    case 12: tr(vwv, W+W_VWV,32,32); break;
    case 13: tr(vwsv, W+W_VWSV,32,128); break;
  }
}

// ---------------- k1: weight_proj logits ----------------
__global__ __launch_bounds__(256) void k1_logits(const float* __restrict__ s,
    const float* __restrict__ v, const float* __restrict__ wpb, float* __restrict__ ws){
  __shared__ __align__(16) float wh_t[1024];
  __shared__ __align__(16) float ws_t[5120];
  __shared__ __align__(16) float cat[8][CAT_];
  __shared__ __align__(16) float vb[8][96];
  int t = threadIdx.x;
  const float* W = ws + OFF_W;
  for(int i=t;i<1024;i+=256) wh_t[i]=W[W_WPWH+i];
  for(int i=t;i<5120;i+=256) ws_t[i]=W[W_WPWS+i];
  __syncthreads();
  int g = t>>5, lane = t&31;
  for(int it=0; it<8; it++){
    long inst = ((long)(blockIdx.x + it*2048))*8 + g;   // n*16+c
    ((float4*)cat[g])[lane] = ((const float4*)s)[inst*32 + lane];
    if(lane<24) ((float4*)vb[g])[lane] = ((const float4*)v)[inst*24 + lane];
    __syncthreads();
    float d0=0.f,d1=0.f,d2=0.f;
    #pragma unroll
    for(int i=0;i<32;i++){
      float w_ = wh_t[i*32+lane];
      d0 += vb[g][3*i]*w_; d1 += vb[g][3*i+1]*w_; d2 += vb[g][3*i+2]*w_;
    }
    cat[g][128+lane] = sqrtf(fmaxf(d0*d0+d1*d1+d2*d2, 1e-8f));
    __syncthreads();
    float acc = wpb[lane];
    #pragma unroll 4
    for(int j=0;j<CAT_;j+=4){
      float4 c4 = *((float4*)&cat[g][j]);
      acc += c4.x*ws_t[j*32+lane] + c4.y*ws_t[(j+1)*32+lane]
           + c4.z*ws_t[(j+2)*32+lane] + c4.w*ws_t[(j+3)*32+lane];
    }
    ws[OFF_LOGITS + inst*32 + lane] = acc;
    __syncthreads();
  }
}

// ---------------- k2a: per-chunk softmax stats ----------------
__global__ __launch_bounds__(256) void k2a_stats(float* __restrict__ ws){
  int c = blockIdx.x; int chunk = blockIdx.y;
  int t=threadIdx.x; int i=t>>5, a=t&31;
  const float* L = ws + OFF_LOGITS;
  float m=-1e30f, sum=0.f;
  for(int k2=0;k2<32;k2++){
    int n = chunk*256 + k2*8 + i;
    float x = L[((long)n*16 + c)*32 + a];
    float mn = fmaxf(m,x);
    sum = sum*__expf(m-mn) + __expf(x-mn);
    m = mn;
  }
  __shared__ float sm[8][32], ss[8][32];
  sm[i][a]=m; ss[i][a]=sum;
  __syncthreads();
  if(t<32){
    float M=sm[0][t], S=ss[0][t];
    for(int q=1;q<8;q++){
      float mq=sm[q][t], sq_=ss[q][t];
      float mn=fmaxf(M,mq); S=S*__expf(M-mn)+sq_*__expf(mq-mn); M=mn;
    }
    ws[OFF_PM + (chunk*16+c)*32 + t]=M;
    ws[OFF_PS + (chunk*16+c)*32 + t]=S;
  }
}

// ---------------- k2b: merge stats ----------------
__global__ __launch_bounds__(256) void k2b_merge(float* __restrict__ ws){
  int t = blockIdx.x*256 + threadIdx.x;
  if(t>=512) return;
  int c=t>>5, a=t&31;
  float M=-1e30f, S=0.f;
  for(int ch=0; ch<32; ch++){
    float mq=ws[OFF_PM+(ch*16+c)*32+a], sq_=ws[OFF_PS+(ch*16+c)*32+a];
    float mn=fmaxf(M,mq); S=S*__expf(M-mn)+sq_*__expf(mq-mn); M=mn;
  }
  ws[OFF_M + t]=M; ws[OFF_INV + t]=1.0f/S;
}

// ---------------- k3: s_global / v_global weighted sums ----------------
__global__ __launch_bounds__(256) void k3_globals(const float* __restrict__ s,
    const float* __restrict__ v, float* __restrict__ ws){
  int c = blockIdx.x & 15; int chunk = blockIdx.x >> 4;   // grid 512
  int t=threadIdx.x; int wave=t>>6, lane=t&63;
  float M=0.f, INV=0.f;
  if(lane<32){ M=ws[OFF_M+c*32+lane]; INV=ws[OFF_INV+c*32+lane]; }
  float4 acc[32];
  #pragma unroll
  for(int a2=0;a2<32;a2++) acc[a2]=make_float4(0.f,0.f,0.f,0.f);
  const float4* s4=(const float4*)s; const float4* v4=(const float4*)v;
  const float* L = ws+OFF_LOGITS;
  for(int it=0; it<64; it++){
    int n = chunk*256 + it*4 + wave;
    long inst = (long)n*16 + c;
    float4 x = make_float4(0.f,0.f,0.f,0.f);
    float w = 0.f;
    if(lane<32){ x = s4[inst*32+lane]; w = __expf(L[inst*32+lane] - M)*INV; }
    else if(lane<56){ x = v4[inst*24 + (lane-32)]; }
    #pragma unroll
    for(int a2=0;a2<32;a2++){
      float wa = __shfl(w, a2, 64);
      acc[a2].x += wa*x.x; acc[a2].y += wa*x.y; acc[a2].z += wa*x.z; acc[a2].w += wa*x.w;
    }
  }
  __shared__ float sacc[32][228];
  float* sf = &sacc[0][0];
  for(int idx=t; idx<32*228; idx+=256) sf[idx]=0.f;
  __syncthreads();
  if(lane<56){
    int db = (lane<32)? lane*4 : 128 + (lane-32)*4;
    #pragma unroll
    for(int a2=0;a2<32;a2++){
      atomicAdd(&sacc[a2][db+0], acc[a2].x);
      atomicAdd(&sacc[a2][db+1], acc[a2].y);
      atomicAdd(&sacc[a2][db+2], acc[a2].z);
      atomicAdd(&sacc[a2][db+3], acc[a2].w);
    }
  }
  __syncthreads();
  for(int idx=t; idx<32*224; idx+=256){
    int a2=idx/224, d=idx-a2*224;
    float val = sacc[a2][d];
    if(d<128) atomicAdd(&ws[OFF_SGL + ((long)a2*16+c)*128 + d], val);
    else      atomicAdd(&ws[OFF_VGL + ((long)a2*16+c)*96 + (d-128)], val);
  }
}

// ---------------- k4: k / val GVPs on globals ----------------
__global__ __launch_bounds__(64) void k4_kvgvp(float* __restrict__ ws,
    const float* __restrict__ k_wsb, const float* __restrict__ k_wsvb,
    const float* __restrict__ v_wsb, const float* __restrict__ v_wsvb){
  int a = blockIdx.x >> 4, c = blockIdx.x & 15;
  int lane = threadIdx.x;
  __shared__ __align__(16) float cat[CAT_];
  __shared__ __align__(16) float vb2[96];
  __shared__ float vhb[96];
  __shared__ __align__(16) float sg[128];
  const float* W = ws + OFF_W;
  long inst = (long)a*16 + c;
  ((float2*)cat)[lane] = ((const float2*)(ws+OFF_SGL))[inst*64 + lane];
  if(lane<48) ((float2*)vb2)[lane] = ((const float2*)(ws+OFF_VGL))[inst*48 + lane];
  __syncthreads();
  int h = lane&31, half = lane>>5;
  for(int p=0;p<2;p++){
    const float* wht  = W + (p? W_VWH  : W_KWH);
    const float* wst  = W + (p? W_VWS  : W_KWS);
    const float* wvt  = W + (p? W_VWV  : W_KWV);
    const float* wsvt = W + (p? W_VWSV : W_KWSV);
    const float* bs   = p? v_wsb : k_wsb;
    const float* bsv  = p? v_wsvb : k_wsvb;
    float d0=0.f,d1=0.f,d2=0.f;
    for(int i=half*16; i<half*16+16; i++){
      float w_=wht[i*32+h];
      d0+=vb2[3*i]*w_; d1+=vb2[3*i+1]*w_; d2+=vb2[3*i+2]*w_;
    }
    d0 += __shfl_xor(d0,32,64); d1 += __shfl_xor(d1,32,64); d2 += __shfl_xor(d2,32,64);
    if(lane<32){
      cat[128+h] = sqrtf(fmaxf(d0*d0+d1*d1+d2*d2, 1e-8f));
      vhb[3*h]=d0; vhb[3*h+1]=d1; vhb[3*h+2]=d2;
    }
    __syncthreads();
    float a0=bs[lane], a1=bs[lane+64];
    for(int j=0;j<160;j+=4){
      float4 c4=*((float4*)&cat[j]);
      a0 += c4.x*wst[j*128+lane]      + c4.y*wst[(j+1)*128+lane]
          + c4.z*wst[(j+2)*128+lane]  + c4.w*wst[(j+3)*128+lane];
      a1 += c4.x*wst[j*128+64+lane]   + c4.y*wst[(j+1)*128+64+lane]
          + c4.z*wst[(j+2)*128+64+lane]+ c4.w*wst[(j+3)*128+64+lane];
    }
    float sig0=1.f/(1.f+__expf(-a0)), sig1=1.f/(1.f+__expf(-a1));
    float silu0=a0*sig0, silu1=a1*sig1;
    sg[lane]=sig0; sg[lane+64]=sig1;
    int o2=lane+64;
    if(p==0){
      ws[OFF_KS + ((long)(c*4 + (lane>>5))*32 + (lane&31))*32 + a] = silu0;
      ws[OFF_KS + ((long)(c*4 + (o2>>5))*32 + (o2&31))*32 + a] = silu1;
    } else {
      ws[OFF_VSC + ((long)(c*4 + (lane>>5))*32 + a)*32 + (lane&31)] = silu0;
      ws[OFF_VSC + ((long)(c*4 + (o2>>5))*32 + a)*32 + (o2&31)] = silu1;
    }
    __syncthreads();
    float gacc=0.f;
    for(int o=half*64; o<half*64+64; o+=4){
      float4 s4_=*((float4*)&sg[o]);
      gacc += s4_.x*wsvt[o*32+h]+s4_.y*wsvt[(o+1)*32+h]+s4_.z*wsvt[(o+2)*32+h]+s4_.w*wsvt[(o+3)*32+h];
    }
    gacc += __shfl_xor(gacc,32,64);
    float sgate = 1.f/(1.f+__expf(-(gacc + bsv[h])));
    float e0=0.f,e1=0.f,e2=0.f;
    for(int hh=half*16; hh<half*16+16; hh++){
      float w_=wvt[hh*32+h];
      e0+=vhb[3*hh]*w_; e1+=vhb[3*hh+1]*w_; e2+=vhb[3*hh+2]*w_;
    }
    e0+=__shfl_xor(e0,32,64); e1+=__shfl_xor(e1,32,64); e2+=__shfl_xor(e2,32,64);
    if(lane<32){
      int o=lane; int ho=o>>3, od=(o&7)*3;
      if(p==0){
        long base = OFF_KV + (long)(c*4+ho)*24*32;
        ws[base + (od+0)*32 + a] = e0*sgate;
        ws[base + (od+1)*32 + a] = e1*sgate;
        ws[base + (od+2)*32 + a] = e2*sgate;
      } else {
        long base = OFF_VVC + ((long)(c*4+ho)*32 + a)*24;
        ws[base + od+0] = e0*sgate; ws[base + od+1] = e1*sgate; ws[base + od+2] = e2*sgate;
      }
    }
    __syncthreads();
  }
}

// ---------------- k5a: q-GVP (writes q into d_out as scratch) ----------------
__global__ __launch_bounds__(256) void k5a_qgvp(const float* __restrict__ s,
    const float* __restrict__ v, const float* __restrict__ ws,
    const float* __restrict__ q_wsb, const float* __restrict__ q_wsvb,
    float* __restrict__ qout){
  __shared__ __align__(16) uint32_t wsb[64*164];
  __shared__ __align__(16) float cat[4][CAT_];
  __shared__ __align__(16) float vb2[4][96];
  __shared__ float vhb[4][96];
  __shared__ __align__(16) float sg[4][128];
  int t=threadIdx.x, wave=t>>6, lane=t&63;
  int c = blockIdx.y, nbase = blockIdx.x*128;
  const uint32_t* gw = (const uint32_t*)(ws + OFF_W + W_QWSB);
  for(int i=t;i<64*164;i+=256) wsb[i]=gw[i];
  const float* wht  = ws+OFF_W+W_QWH;
  const float* wvt  = ws+OFF_W+W_QWV;
  const float* wsvt = ws+OFF_W+W_QWSV;
  float b0 = q_wsb[2*lane], b1 = q_wsb[2*lane+1];
  float bsv_ = q_wsvb[lane&31];
  __syncthreads();
  float* qs_out = qout;
  float* qv_out = qout + (long)N_*C_*SI_;
  int h=lane&31, half=lane>>5;
  const uint32_t* wrow = &wsb[lane*164];
  for(int it=0; it<32; it++){
    int n = nbase + it*4 + wave;
    long inst = (long)n*16 + c;
    ((float2*)cat[wave])[lane] = ((const float2*)s)[inst*64+lane];
    if(lane<48) ((float2*)vb2[wave])[lane] = ((const float2*)v)[inst*48+lane];
    __syncthreads();
    float d0=0.f,d1=0.f,d2=0.f;
    for(int i=half*16;i<half*16+16;i++){
      float w_=wht[i*32+h];
      d0+=vb2[wave][3*i]*w_; d1+=vb2[wave][3*i+1]*w_; d2+=vb2[wave][3*i+2]*w_;
    }
    d0+=__shfl_xor(d0,32,64); d1+=__shfl_xor(d1,32,64); d2+=__shfl_xor(d2,32,64);
    if(lane<32){
      cat[wave][128+h]=sqrtf(fmaxf(d0*d0+d1*d1+d2*d2,1e-8f));
      vhb[wave][3*h]=d0; vhb[wave][3*h+1]=d1; vhb[wave][3*h+2]=d2;
    }
    __syncthreads();
    float a0=b0, a1=b1;
    #pragma unroll 4
    for(int j=0;j<160;j+=4){
      float4 c4=*((float4*)&cat[wave][j]);
      uint4 u4=*((const uint4*)&wrow[j]);
      a0 += c4.x*__uint_as_float(u4.x<<16) + c4.y*__uint_as_float(u4.y<<16)
          + c4.z*__uint_as_float(u4.z<<16) + c4.w*__uint_as_float(u4.w<<16);
      a1 += c4.x*__uint_as_float(u4.x&0xFFFF0000u) + c4.y*__uint_as_float(u4.y&0xFFFF0000u)
          + c4.z*__uint_as_float(u4.z&0xFFFF0000u) + c4.w*__uint_as_float(u4.w&0xFFFF0000u);
    }
    float sig0=1.f/(1.f+__expf(-a0)), sig1=1.f/(1.f+__expf(-a1));
    float silu0=a0*sig0, silu1=a1*sig1;
    sg[wave][2*lane]=sig0; sg[wave][2*lane+1]=sig1;
    ((float2*)&qs_out[inst*128])[lane] = make_float2(silu0, silu1);
    __syncthreads();
    float gacc=0.f;
    for(int o=half*64;o<half*64+64;o+=4){
      float4 s4_=*((float4*)&sg[wave][o]);
      gacc += s4_.x*wsvt[o*32+h]+s4_.y*wsvt[(o+1)*32+h]+s4_.z*wsvt[(o+2)*32+h]+s4_.w*wsvt[(o+3)*32+h];
    }
    gacc+=__shfl_xor(gacc,32,64);
    float sgate=1.f/(1.f+__expf(-(gacc+bsv_)));
    float e0=0.f,e1=0.f,e2=0.f;
    for(int hh=half*16;hh<half*16+16;hh++){
      float w_=wvt[hh*32+h];
      e0+=vhb[wave][3*hh]*w_; e1+=vhb[wave][3*hh+1]*w_; e2+=vhb[wave][3*hh+2]*w_;
    }
    e0+=__shfl_xor(e0,32,64); e1+=__shfl_xor(e1,32,64); e2+=__shfl_xor(e2,32,64);
    if(lane<32){
      float* dst=&qv_out[inst*96 + 3*h];
      dst[0]=e0*sgate; dst[1]=e1*sgate; dst[2]=e2*sgate;
    }
    __syncthreads();
  }
}

// ---------------- k5b: attention (reads q from d_out, overwrites with final) ----------------
__global__ __launch_bounds__(256) void k5b_attn(const float* __restrict__ ws, float* __restrict__ qio){
  __shared__ float ksl[4096];   // [(h*32+j)*32 + r]
  __shared__ float kvl[3072];   // [(h*24+od)*32 + r]
  __shared__ float vsl[4096];   // [(h*32+r)*32 + j]
  __shared__ float vvl[3072];   // [(h*32+r)*24 + od]
  __shared__ __align__(16) float sq[4][128];
  __shared__ __align__(16) float qv[4][96];
  __shared__ float ab[4][128];
  int t=threadIdx.x, wave=t>>6, lane=t&63;
  int c=blockIdx.y, nbase=blockIdx.x*128;
  for(int i=t;i<4096;i+=256){ ksl[i]=ws[OFF_KS + (long)c*4096 + i]; vsl[i]=ws[OFF_VSC + (long)c*4096 + i]; }
  for(int i=t;i<3072;i+=256){ kvl[i]=ws[OFF_KV + (long)c*3072 + i]; vvl[i]=ws[OFF_VVC + (long)c*3072 + i]; }
  __syncthreads();
  const float* qs_in = qio;
  const float* qv_in = qio + (long)N_*C_*SI_;
  float* outs = qio;
  float* outv = qio + (long)N_*C_*SI_;
  const float scale = 0.15811388300841897f;  // 1/sqrt(40)
  for(int it=0;it<32;it++){
    int n = nbase + it*4 + wave;
    long inst=(long)n*16+c;
    ((float2*)sq[wave])[lane] = ((const float2*)&qs_in[inst*128])[lane];
    if(lane<48) ((float2*)qv[wave])[lane]=((const float2*)&qv_in[inst*96])[lane];
    __syncthreads();
    for(int hh=0; hh<2; hh++){
      int h_ = hh*2 + (lane>>5), r = lane&31;
      float e=0.f;
      const float* qrow=&sq[wave][h_*32];
      const float* krow=&ksl[h_*32*32];
      #pragma unroll
      for(int j=0;j<32;j++) e += qrow[j]*krow[j*32+r];
      const float* q2=&qv[wave][h_*24];
      const float* k2=&kvl[h_*24*32];
      #pragma unroll
      for(int od=0;od<24;od++) e += q2[od]*k2[od*32+r];
      e *= scale;
      float m=e;
      #pragma unroll
      for(int off=16;off>0;off>>=1) m=fmaxf(m,__shfl_xor(m,off,64));
      float p=__expf(e-m), ssum=p;
      #pragma unroll
      for(int off=16;off>0;off>>=1) ssum+=__shfl_xor(ssum,off,64);
      ab[wave][h_*32+r]=p/ssum;
    }
    __syncthreads();
    for(int hh=0;hh<2;hh++){
      int h_=hh*2+(lane>>5), j=lane&31;
      float o=0.f;
      const float* arow=&ab[wave][h_*32];
      const float* vrow=&vsl[h_*32*32];
      #pragma unroll
      for(int r2=0;r2<32;r2++) o += arow[r2]*vrow[r2*32+j];
      outs[inst*128 + hh*64 + lane] = o;
    }
    {
      int ov=lane; int h_=ov/24, od=ov-h_*24;
      float o=0.f;
      const float* arow=&ab[wave][h_*32];
      const float* vrow=&vvl[h_*32*24];
      #pragma unroll
      for(int r2=0;r2<32;r2++) o += arow[r2]*vrow[r2*24+od];
      outv[inst*96+ov]=o;
      if(lane<32){
        int ov2=64+lane; int h2=ov2/24, od2=ov2-h2*24;
        float o2=0.f;
        const float* arow2=&ab[wave][h2*32];
        const float* vrow2=&vvl[h2*32*24];
        #pragma unroll
        for(int r2=0;r2<32;r2++) o2 += arow2[r2]*vrow2[r2*24+od2];
        outv[inst*96+ov2]=o2;
      }
    }
    __syncthreads();
  }
}

extern "C" void kernel_launch(void* const* d_in, const int* in_sizes, int n_in,
                              void* d_out, int out_size, void* d_ws, size_t ws_size,
                              hipStream_t stream){
  (void)in_sizes; (void)n_in; (void)out_size; (void)ws_size;
  const float* s = (const float*)d_in[0];
  const float* v = (const float*)d_in[1];
  float* ws = (float*)d_ws;
  float* out = (float*)d_out;
  // zero the atomic-accumulated global buffers
  hipMemsetAsync((char*)d_ws + OFF_SGL*sizeof(float), 0, (size_t)(SZ_SGL+SZ_VGL)*sizeof(float), stream);
  k0_transpose<<<14,256,0,stream>>>(
      (const float*)d_in[2],(const float*)d_in[3],
      (const float*)d_in[5],(const float*)d_in[6],(const float*)d_in[8],(const float*)d_in[9],
      (const float*)d_in[11],(const float*)d_in[12],(const float*)d_in[14],(const float*)d_in[15],
      (const float*)d_in[17],(const float*)d_in[18],(const float*)d_in[20],(const float*)d_in[21], ws);
  k1_logits<<<2048,256,0,stream>>>(s, v, (const float*)d_in[4], ws);
  k2a_stats<<<dim3(16,32),256,0,stream>>>(ws);
  k2b_merge<<<2,256,0,stream>>>(ws);
  k3_globals<<<512,256,0,stream>>>(s, v, ws);
  k4_kvgvp<<<512,64,0,stream>>>(ws, (const float*)d_in[13], (const float*)d_in[16],
                                (const float*)d_in[19], (const float*)d_in[22]);
  k5a_qgvp<<<dim3(64,16),256,0,stream>>>(s, v, ws, (const float*)d_in[7], (const float*)d_in[10], out);
  k5b_attn<<<dim3(64,16),256,0,stream>>>(ws, out);
}

// Round 3
// 594.857 us; speedup vs baseline: 1.8587x; 1.8587x over previous
//
#include <hip/hip_runtime.h>
#include <stdint.h>

typedef unsigned short ushort_t;
typedef __attribute__((ext_vector_type(8))) short short8;   // 8 x bf16 bits
typedef __attribute__((ext_vector_type(4))) float float4v;  // MFMA C/D frag

static constexpr int N_=8192, C_=16;

// ---- ws layout (float offsets) ----
static constexpr long OFF_LOGITS = 0;                      // fp32 [131072][32]
static constexpr long OFF_PM  = 4194304;                   // [32][16][32]
static constexpr long OFF_PS  = 4210688;
static constexpr long OFF_M   = 4227072;                   // [16][32]
static constexpr long OFF_INV = 4227584;
static constexpr long OFF_SGL = 4228096;                   // fp32 [32][16][128]
static constexpr long OFF_VGL = 4293632;                   // fp32 [32][16][96]
static constexpr long OFF_KATT= 4342784;                   // bf16 [c][h][kt2][nt2][64][8]
static constexpr long OFF_VATT= 4408320;                   // bf16 [c][h][nt4][64][8]
static constexpr long OFF_WF  = 4473856;
// sub-offsets (floats) in OFF_WF region
static constexpr long WF_WHQ=0, WF_WHWP=1024, WF_KWH=2048, WF_KWS=3072, WF_KWV=23552,
  WF_KWSV=24576, WF_VWH=28672, WF_VWS=29696, WF_VWV=50176, WF_VWSV=51200,
  WF_B1=55296 /*bf16[6][10][64][8]*/, WF_BG=70656 /*bf16[4][2][64][8]*/,
  WF_BV=72704 /*bf16[2][64][8]*/;

// ---- d_out scratch byte offsets (all consumed before final outputs written) ----
static constexpr long VH_B   = 67108864;   // bf16 [131072*3][32]   (in out_v region, dead before k5)
static constexpr long AVN_B  = 92274688;   // bf16 [131072][64]     (in out_v region, dead before k5)

__device__ __forceinline__ uint32_t f2bf(float f){
  uint32_t u = __float_as_uint(f);
  return (u + 0x7FFFu + ((u>>16)&1u)) >> 16;
}

// B-fragment index helpers for mfma_f32_16x16x32_bf16:
// B[k][n] lives at lane = ((k&31)>>3)*16 + (n&15), j = k&7, tile nt = n>>4 (n in 0..31), kt = k>>5.
__device__ __forceinline__ long katt_idx(int c, int h, int k, int r){
  int kt=k>>5, kk=k&31, nt=r>>4;
  int lane=((kk>>3)<<4)|(r&15), j=kk&7;
  return ((((long)(c*4+h)*2+kt)*2+nt)*64+lane)*8+j;
}
__device__ __forceinline__ long vatt_idx(int c, int h, int r, int n2){
  int nt=n2>>4;
  int lane=((r>>3)<<4)|(n2&15), j=r&7;
  return (((long)(c*4+h)*4+nt)*64+lane)*8+j;
}

// ================= k0: weight prep (transposes + bf16 B-fragments) =================
__global__ void k0_prep(const float* __restrict__ wpwh, const float* __restrict__ wpws,
    const float* __restrict__ qwh, const float* __restrict__ qws, const float* __restrict__ qwv,
    const float* __restrict__ qwsv, const float* __restrict__ kwh, const float* __restrict__ kws,
    const float* __restrict__ kwv, const float* __restrict__ kwsv, const float* __restrict__ vwh,
    const float* __restrict__ vws, const float* __restrict__ vwv, const float* __restrict__ vwsv,
    float* __restrict__ wsf){
  int job=blockIdx.x, t=threadIdx.x;
  float* W = wsf + OFF_WF;
  auto tr=[&](const float* src, float* dst, int O, int J){
    for(int idx=t; idx<O*J; idx+=blockDim.x){int o=idx/J, j=idx-o*J; dst[j*O+o]=src[idx];}
  };
  switch(job){
    case 0: tr(qwh,  W+WF_WHQ, 32,32); break;
    case 1: tr(wpwh, W+WF_WHWP,32,32); break;
    case 2: tr(kwh,  W+WF_KWH, 32,32); break;
    case 3: tr(kws,  W+WF_KWS, 128,160); break;
    case 4: tr(kwv,  W+WF_KWV, 32,32); break;
    case 5: tr(kwsv, W+WF_KWSV,32,128); break;
    case 6: tr(vwh,  W+WF_VWH, 32,32); break;
    case 7: tr(vws,  W+WF_VWS, 128,160); break;
    case 8: tr(vwv,  W+WF_VWV, 32,32); break;
    case 9: tr(vwsv, W+WF_VWSV,32,128); break;
    case 10: { // B1[k 192][n 160]: k<128 -> s; 128..159 -> vn_q; 160..191 -> vn_wp
      ushort_t* dst=(ushort_t*)(W+WF_B1);
      for(int idx=t; idx<30720; idx+=blockDim.x){
        int j=idx&7, lane=(idx>>3)&63, tn=idx>>9, nt=tn%10, kt=tn/10;
        int k=kt*32+((lane>>4)<<3)+j, n=nt*16+(lane&15);
        float val;
        if(k<128)       val = (n<128)? qws[n*160+k]            : wpws[(n-128)*160+k];
        else if(k<160)  val = (n<128)? qws[n*160+k]            : 0.f;
        else            val = (n<128)? 0.f                     : wpws[(n-128)*160+(k-32)];
        dst[idx]=(ushort_t)f2bf(val);
      } } break;
    case 11: { // gate B: wsv^T [128][32]
      ushort_t* dst=(ushort_t*)(W+WF_BG);
      for(int idx=t; idx<4096; idx+=blockDim.x){
        int j=idx&7, lane=(idx>>3)&63, tn=idx>>9, nt=tn&1, kt=tn>>1;
        int k=kt*32+((lane>>4)<<3)+j, n=nt*16+(lane&15);
        dst[idx]=(ushort_t)f2bf(qwsv[n*128+k]);
      } } break;
    case 12: { // v_out B: wv^T [32][32]
      ushort_t* dst=(ushort_t*)(W+WF_BV);
      for(int idx=t; idx<1024; idx+=blockDim.x){
        int j=idx&7, lane=(idx>>3)&63, nt=idx>>9;
        int k=((lane>>4)<<3)+j, n=nt*16+(lane&15);
        dst[idx]=(ushort_t)f2bf(qwv[n*32+k]);
      } } break;
  }
}

// ================= kA: vh_q / vn_q / vn_wp (VALU, small) =================
__global__ __launch_bounds__(256) void kA_vn(const float* __restrict__ v,
    const float* __restrict__ wsf, ushort_t* __restrict__ vh_s, ushort_t* __restrict__ avn_s){
  __shared__ float whq[1024], whwp[1024];
  __shared__ float vb[4][96];
  int t=threadIdx.x, wave=t>>6, lane=t&63;
  for(int i=t;i<1024;i+=256){ whq[i]=wsf[OFF_WF+WF_WHQ+i]; whwp[i]=wsf[OFF_WF+WF_WHWP+i]; }
  __syncthreads();
  int h=lane&31, half=lane>>5;
  for(int it=0; it<32; it++){
    long inst = ((long)blockIdx.x*4 + wave)*32 + it;
    if(lane<48) ((float2*)vb[wave])[lane] = ((const float2*)v)[inst*48+lane];
    float d0=0,d1=0,d2=0;
    for(int i=half*16;i<half*16+16;i++){ float w=whq[i*32+h];
      d0+=vb[wave][3*i]*w; d1+=vb[wave][3*i+1]*w; d2+=vb[wave][3*i+2]*w; }
    d0+=__shfl_xor(d0,32,64); d1+=__shfl_xor(d1,32,64); d2+=__shfl_xor(d2,32,64);
    if(lane<32){
      float vn=sqrtf(fmaxf(d0*d0+d1*d1+d2*d2,1e-8f));
      avn_s[inst*64+h]=(ushort_t)f2bf(vn);
      vh_s[(inst*3+0)*32+h]=(ushort_t)f2bf(d0);
      vh_s[(inst*3+1)*32+h]=(ushort_t)f2bf(d1);
      vh_s[(inst*3+2)*32+h]=(ushort_t)f2bf(d2);
    }
    float e0=0,e1=0,e2=0;
    for(int i=half*16;i<half*16+16;i++){ float w=whwp[i*32+h];
      e0+=vb[wave][3*i]*w; e1+=vb[wave][3*i+1]*w; e2+=vb[wave][3*i+2]*w; }
    e0+=__shfl_xor(e0,32,64); e1+=__shfl_xor(e1,32,64); e2+=__shfl_xor(e2,32,64);
    if(lane<32){
      float vn=sqrtf(fmaxf(e0*e0+e1*e1+e2*e2,1e-8f));
      avn_s[inst*64+32+h]=(ushort_t)f2bf(vn);
    }
  }
}

// ================= kB: fused MFMA GEMM (q s_out + wp logits + gate + v_out) =================
__global__ __launch_bounds__(256) void kB_gemm(const float* __restrict__ s,
    float* __restrict__ wsf,
    const float* __restrict__ qwsb, const float* __restrict__ wpwsb,
    const float* __restrict__ qwsvb,
    ushort_t* __restrict__ qatt, const ushort_t* __restrict__ vh_s,
    const ushort_t* __restrict__ avn_s){
  __shared__ ushort_t sigl[4][16*136];   // sigmoid(s_out) bf16, rows padded to 136
  __shared__ float    gsigl[4][16*33];   // sigmoid(gate) fp32
  int t=threadIdx.x, wave=t>>6, lane=t&63;
  int l15=lane&15, lq=lane>>4;
  long m0 = ((long)blockIdx.x*4 + wave)*16;
  const short8* B1 = (const short8*)(wsf + OFF_WF + WF_B1);
  const short8* BG = (const short8*)(wsf + OFF_WF + WF_BG);
  const short8* BV = (const short8*)(wsf + OFF_WF + WF_BV);
  float4v acc[10];
  #pragma unroll
  for(int i=0;i<10;i++) acc[i]=(float4v){0.f,0.f,0.f,0.f};
  // K 0..127: s (fp32 -> bf16 on the fly)
  #pragma unroll
  for(int kt=0;kt<4;kt++){
    const float* sp = s + (m0+l15)*128 + kt*32 + lq*8;
    float4 f0=*(const float4*)sp, f1=*(const float4*)(sp+4);
    short8 a;
    a[0]=(short)f2bf(f0.x); a[1]=(short)f2bf(f0.y); a[2]=(short)f2bf(f0.z); a[3]=(short)f2bf(f0.w);
    a[4]=(short)f2bf(f1.x); a[5]=(short)f2bf(f1.y); a[6]=(short)f2bf(f1.z); a[7]=(short)f2bf(f1.w);
    #pragma unroll
    for(int nt=0;nt<10;nt++)
      acc[nt]=__builtin_amdgcn_mfma_f32_16x16x32_bf16(a, B1[(kt*10+nt)*64+lane], acc[nt],0,0,0);
  }
  // K 128..191: [vn_q | vn_wp]
  #pragma unroll
  for(int kt=4;kt<6;kt++){
    short8 a = *(const short8*)&avn_s[(m0+l15)*64 + (kt-4)*32 + lq*8];
    #pragma unroll
    for(int nt=0;nt<10;nt++)
      acc[nt]=__builtin_amdgcn_mfma_f32_16x16x32_bf16(a, B1[(kt*10+nt)*64+lane], acc[nt],0,0,0);
  }
  ushort_t* sl = sigl[wave]; float* gl = gsigl[wave];
  // epilogue: silu -> q_att (bf16), sigmoid -> LDS; logits -> ws (fp32)
  #pragma unroll
  for(int nt=0;nt<8;nt++){
    float b = qwsb[nt*16+l15];
    #pragma unroll
    for(int reg=0;reg<4;reg++){
      float x = acc[nt][reg] + b;
      float sg = 1.f/(1.f+__expf(-x));
      int row = lq*4+reg, col=nt*16+l15;
      long inst = m0+row;
      qatt[(inst*4 + (col>>5))*64 + (col&31)] = (ushort_t)f2bf(x*sg);
      sl[row*136+col] = (ushort_t)f2bf(sg);
    }
  }
  #pragma unroll
  for(int nt=8;nt<10;nt++){
    float b = wpwsb[(nt-8)*16+l15];
    #pragma unroll
    for(int reg=0;reg<4;reg++){
      long inst=m0+lq*4+reg;
      wsf[OFF_LOGITS + inst*32 + (nt-8)*16+l15] = acc[nt][reg]+b;
    }
  }
  __syncthreads();
  // gate GEMM: sigmoid(s_out)[16x128] @ wsv^T[128x32]
  float4v g0=(float4v){0.f,0.f,0.f,0.f}, g1=g0;
  #pragma unroll
  for(int kt=0;kt<4;kt++){
    short8 a = *(const short8*)&sl[l15*136 + kt*32 + lq*8];
    g0=__builtin_amdgcn_mfma_f32_16x16x32_bf16(a, BG[(kt*2+0)*64+lane], g0,0,0,0);
    g1=__builtin_amdgcn_mfma_f32_16x16x32_bf16(a, BG[(kt*2+1)*64+lane], g1,0,0,0);
  }
  {
    float b0 = qwsvb[l15], b1 = qwsvb[16+l15];
    #pragma unroll
    for(int reg=0;reg<4;reg++){
      int row=lq*4+reg;
      gl[row*33 + l15]    = 1.f/(1.f+__expf(-(g0[reg]+b0)));
      gl[row*33 + 16+l15] = 1.f/(1.f+__expf(-(g1[reg]+b1)));
    }
  }
  __syncthreads();
  // v_out GEMM: vh[(inst,d) x 32] @ wv^T[32x32], gated, -> q_att qv part (bf16)
  #pragma unroll
  for(int tt=0;tt<3;tt++){
    short8 a = *(const short8*)&vh_s[(m0*3 + tt*16 + l15)*32 + lq*8];
    float4v v0=(float4v){0.f,0.f,0.f,0.f}, v1=v0;
    v0=__builtin_amdgcn_mfma_f32_16x16x32_bf16(a, BV[0*64+lane], v0,0,0,0);
    v1=__builtin_amdgcn_mfma_f32_16x16x32_bf16(a, BV[1*64+lane], v1,0,0,0);
    #pragma unroll
    for(int nt2=0;nt2<2;nt2++){
      #pragma unroll
      for(int reg=0;reg<4;reg++){
        int lr = tt*16 + lq*4 + reg;
        int il = lr/3, d = lr - il*3;
        int o = nt2*16+l15;
        float val = (nt2? v1[reg] : v0[reg]) * gl[il*33+o];
        long inst = m0 + il;
        qatt[(inst*4 + (o>>3))*64 + 32 + (o&7)*3 + d] = (ushort_t)f2bf(val);
      }
    }
  }
}

// ================= k2a/k2b: softmax-over-N stats =================
__global__ __launch_bounds__(256) void k2a_stats(float* __restrict__ ws){
  int c = blockIdx.x; int chunk = blockIdx.y;
  int t=threadIdx.x; int i=t>>5, a=t&31;
  const float* L = ws + OFF_LOGITS;
  float m=-1e30f, sum=0.f;
  for(int k2=0;k2<32;k2++){
    int n = chunk*256 + k2*8 + i;
    float x = L[((long)n*16 + c)*32 + a];
    float mn = fmaxf(m,x);
    sum = sum*__expf(m-mn) + __expf(x-mn);
    m = mn;
  }
  __shared__ float sm[8][32], ss[8][32];
  sm[i][a]=m; ss[i][a]=sum;
  __syncthreads();
  if(t<32){
    float M=sm[0][t], S=ss[0][t];
    for(int q=1;q<8;q++){
      float mq=sm[q][t], sq_=ss[q][t];
      float mn=fmaxf(M,mq); S=S*__expf(M-mn)+sq_*__expf(mq-mn); M=mn;
    }
    ws[OFF_PM + (chunk*16+c)*32 + t]=M;
    ws[OFF_PS + (chunk*16+c)*32 + t]=S;
  }
}

__global__ __launch_bounds__(256) void k2b_merge(float* __restrict__ ws){
  int t = blockIdx.x*256 + threadIdx.x;
  if(t>=512) return;
  int c=t>>5, a=t&31;
  float M=-1e30f, S=0.f;
  for(int ch=0; ch<32; ch++){
    float mq=ws[OFF_PM+(ch*16+c)*32+a], sq_=ws[OFF_PS+(ch*16+c)*32+a];
    float mn=fmaxf(M,mq); S=S*__expf(M-mn)+sq_*__expf(mq-mn); M=mn;
  }
  ws[OFF_M + t]=M; ws[OFF_INV + t]=1.0f/S;
}

// ================= k3: s_global / v_global weighted sums =================
__global__ __launch_bounds__(256) void k3_globals(const float* __restrict__ s,
    const float* __restrict__ v, float* __restrict__ ws){
  int c = blockIdx.x & 15; int chunk = blockIdx.x >> 4;
  int t=threadIdx.x; int wave=t>>6, lane=t&63;
  float M=0.f, INV=0.f;
  if(lane<32){ M=ws[OFF_M+c*32+lane]; INV=ws[OFF_INV+c*32+lane]; }
  float4 acc[32];
  #pragma unroll
  for(int a2=0;a2<32;a2++) acc[a2]=make_float4(0.f,0.f,0.f,0.f);
  const float4* s4=(const float4*)s; const float4* v4=(const float4*)v;
  const float* L = ws+OFF_LOGITS;
  for(int it=0; it<64; it++){
    int n = chunk*256 + it*4 + wave;
    long inst = (long)n*16 + c;
    float4 x = make_float4(0.f,0.f,0.f,0.f);
    float w = 0.f;
    if(lane<32){ x = s4[inst*32+lane]; w = __expf(L[inst*32+lane] - M)*INV; }
    else if(lane<56){ x = v4[inst*24 + (lane-32)]; }
    #pragma unroll
    for(int a2=0;a2<32;a2++){
      float wa = __shfl(w, a2, 64);
      acc[a2].x += wa*x.x; acc[a2].y += wa*x.y; acc[a2].z += wa*x.z; acc[a2].w += wa*x.w;
    }
  }
  __shared__ float sacc[32][228];
  float* sf = &sacc[0][0];
  for(int idx=t; idx<32*228; idx+=256) sf[idx]=0.f;
  __syncthreads();
  if(lane<56){
    int db = (lane<32)? lane*4 : 128 + (lane-32)*4;
    #pragma unroll
    for(int a2=0;a2<32;a2++){
      atomicAdd(&sacc[a2][db+0], acc[a2].x);
      atomicAdd(&sacc[a2][db+1], acc[a2].y);
      atomicAdd(&sacc[a2][db+2], acc[a2].z);
      atomicAdd(&sacc[a2][db+3], acc[a2].w);
    }
  }
  __syncthreads();
  for(int idx=t; idx<32*224; idx+=256){
    int a2=idx/224, d=idx-a2*224;
    float val = sacc[a2][d];
    if(d<128) atomicAdd(&ws[OFF_SGL + ((long)a2*16+c)*128 + d], val);
    else      atomicAdd(&ws[OFF_VGL + ((long)a2*16+c)*96 + (d-128)], val);
  }
}

// ================= k4: k / val GVPs -> K_att / V_att bf16 fragment buffers =================
__global__ __launch_bounds__(64) void k4_kvgvp(float* __restrict__ wsf,
    const float* __restrict__ k_wsb, const float* __restrict__ k_wsvb,
    const float* __restrict__ v_wsb, const float* __restrict__ v_wsvb){
  int a = blockIdx.x >> 4, c = blockIdx.x & 15;
  int lane = threadIdx.x;
  __shared__ __align__(16) float cat[160];
  __shared__ __align__(16) float vb2[96];
  __shared__ float vhb[96];
  __shared__ __align__(16) float sg[128];
  const float* W = wsf + OFF_WF;
  ushort_t* katt = (ushort_t*)(wsf + OFF_KATT);
  ushort_t* vatt = (ushort_t*)(wsf + OFF_VATT);
  long inst = (long)a*16 + c;
  ((float2*)cat)[lane] = ((const float2*)(wsf+OFF_SGL))[inst*64 + lane];
  if(lane<48) ((float2*)vb2)[lane] = ((const float2*)(wsf+OFF_VGL))[inst*48 + lane];
  __syncthreads();
  if(a==0){ // zero pad slots k=56..63 (K) and n2=56..63 (V), all r, once per (c,h)
    for(int idx=lane; idx<1024; idx+=64){
      int h2=idx&3, kk=56+((idx>>2)&7), r=idx>>5;
      katt[katt_idx(c,h2,kk,r)]=0;
      vatt[vatt_idx(c,h2,r,kk)]=0;
    }
  }
  int h = lane&31, half = lane>>5;
  for(int p=0;p<2;p++){
    const float* wht  = W + (p? WF_VWH  : WF_KWH);
    const float* wst  = W + (p? WF_VWS  : WF_KWS);
    const float* wvt  = W + (p? WF_VWV  : WF_KWV);
    const float* wsvt = W + (p? WF_VWSV : WF_KWSV);
    const float* bs   = p? v_wsb : k_wsb;
    const float* bsv  = p? v_wsvb : k_wsvb;
    float d0=0.f,d1=0.f,d2=0.f;
    for(int i=half*16; i<half*16+16; i++){
      float w_=wht[i*32+h];
      d0+=vb2[3*i]*w_; d1+=vb2[3*i+1]*w_; d2+=vb2[3*i+2]*w_;
    }
    d0 += __shfl_xor(d0,32,64); d1 += __shfl_xor(d1,32,64); d2 += __shfl_xor(d2,32,64);
    if(lane<32){
      cat[128+h] = sqrtf(fmaxf(d0*d0+d1*d1+d2*d2, 1e-8f));
      vhb[3*h]=d0; vhb[3*h+1]=d1; vhb[3*h+2]=d2;
    }
    __syncthreads();
    float a0=bs[lane], a1=bs[lane+64];
    for(int j=0;j<160;j+=4){
      float4 c4=*((float4*)&cat[j]);
      a0 += c4.x*wst[j*128+lane]      + c4.y*wst[(j+1)*128+lane]
          + c4.z*wst[(j+2)*128+lane]  + c4.w*wst[(j+3)*128+lane];
      a1 += c4.x*wst[j*128+64+lane]   + c4.y*wst[(j+1)*128+64+lane]
          + c4.z*wst[(j+2)*128+64+lane]+ c4.w*wst[(j+3)*128+64+lane];
    }
    float sig0=1.f/(1.f+__expf(-a0)), sig1=1.f/(1.f+__expf(-a1));
    float silu0=a0*sig0, silu1=a1*sig1;
    sg[lane]=sig0; sg[lane+64]=sig1;
    // store s-part
    {
      int o=lane, hh2=o>>5, k=o&31;
      if(p==0) katt[katt_idx(c,hh2,k,a)] = (ushort_t)f2bf(silu0);
      else     vatt[vatt_idx(c,hh2,a,k)] = (ushort_t)f2bf(silu0);
    }
    {
      int o=lane+64, hh2=o>>5, k=o&31;
      if(p==0) katt[katt_idx(c,hh2,k,a)] = (ushort_t)f2bf(silu1);
      else     vatt[vatt_idx(c,hh2,a,k)] = (ushort_t)f2bf(silu1);
    }
    __syncthreads();
    float gacc=0.f;
    for(int o=half*64; o<half*64+64; o+=4){
      float4 s4_=*((float4*)&sg[o]);
      gacc += s4_.x*wsvt[o*32+h]+s4_.y*wsvt[(o+1)*32+h]+s4_.z*wsvt[(o+2)*32+h]+s4_.w*wsvt[(o+3)*32+h];
    }
    gacc += __shfl_xor(gacc,32,64);
    float sgate = 1.f/(1.f+__expf(-(gacc + bsv[h])));
    float e0=0.f,e1=0.f,e2=0.f;
    for(int hh=half*16; hh<half*16+16; hh++){
      float w_=wvt[hh*32+h];
      e0+=vhb[3*hh]*w_; e1+=vhb[3*hh+1]*w_; e2+=vhb[3*hh+2]*w_;
    }
    e0+=__shfl_xor(e0,32,64); e1+=__shfl_xor(e1,32,64); e2+=__shfl_xor(e2,32,64);
    if(lane<32){
      int hh2=lane>>3, oo=lane&7;
      float vals[3]={e0*sgate, e1*sgate, e2*sgate};
      #pragma unroll
      for(int d=0;d<3;d++){
        if(p==0) katt[katt_idx(c,hh2,32+oo*3+d,a)] = (ushort_t)f2bf(vals[d]);
        else     vatt[vatt_idx(c,hh2,a,32+oo*3+d)] = (ushort_t)f2bf(vals[d]);
      }
    }
    __syncthreads();
  }
}

// ================= k5: MFMA attention (reads q_att from d_out, overwrites outputs) ===========
__global__ __launch_bounds__(256) void k5_attn(const float* __restrict__ wsf, float* out){
  __shared__ ushort_t al[4][4*16*40];   // alpha bf16, per wave, per h rows padded to 40
  int t=threadIdx.x, wave=t>>6, lane=t&63;
  int l15=lane&15, lq=lane>>4;
  int c=blockIdx.y;
  long n0 = ((long)blockIdx.x*4+wave)*16;
  const ushort_t* qatt = (const ushort_t*)out;    // ALIASES out: all reads precede writes
  const short8* KA = (const short8*)(wsf + OFF_KATT);
  const short8* VA = (const short8*)(wsf + OFF_VATT);
  const float scale = 0.15811388300841897f;  // 1/sqrt(40)
  float4v e[4][2];
  #pragma unroll
  for(int h=0;h<4;h++){ e[h][0]=(float4v){0.f,0.f,0.f,0.f}; e[h][1]=e[h][0]; }
  #pragma unroll
  for(int h=0;h<4;h++){
    #pragma unroll
    for(int kt=0;kt<2;kt++){
      short8 a = *(const short8*)&qatt[(((n0+l15)*16 + c)*4 + h)*64 + kt*32 + lq*8];
      e[h][0]=__builtin_amdgcn_mfma_f32_16x16x32_bf16(a, KA[(((c*4+h)*2+kt)*2+0)*64+lane], e[h][0],0,0,0);
      e[h][1]=__builtin_amdgcn_mfma_f32_16x16x32_bf16(a, KA[(((c*4+h)*2+kt)*2+1)*64+lane], e[h][1],0,0,0);
    }
  }
  ushort_t* alw = al[wave];
  #pragma unroll
  for(int h=0;h<4;h++){
    #pragma unroll
    for(int reg=0;reg<4;reg++){
      float a0=e[h][0][reg]*scale, a1=e[h][1][reg]*scale;
      float m=fmaxf(a0,a1);
      m=fmaxf(m,__shfl_xor(m,1,64)); m=fmaxf(m,__shfl_xor(m,2,64));
      m=fmaxf(m,__shfl_xor(m,4,64)); m=fmaxf(m,__shfl_xor(m,8,64));
      float p0=__expf(a0-m), p1=__expf(a1-m);
      float sum=p0+p1;
      sum+=__shfl_xor(sum,1,64); sum+=__shfl_xor(sum,2,64);
      sum+=__shfl_xor(sum,4,64); sum+=__shfl_xor(sum,8,64);
      float inv=1.f/sum;
      int row=lq*4+reg;
      alw[h*640 + row*40 + l15]      = (ushort_t)f2bf(p0*inv);
      alw[h*640 + row*40 + 16 + l15] = (ushort_t)f2bf(p1*inv);
    }
  }
  __syncthreads();
  float* outv = out + 16777216;
  #pragma unroll
  for(int h=0;h<4;h++){
    short8 a = *(const short8*)&alw[h*640 + l15*40 + lq*8];
    #pragma unroll
    for(int nt=0;nt<4;nt++){
      float4v o_=(float4v){0.f,0.f,0.f,0.f};
      o_=__builtin_amdgcn_mfma_f32_16x16x32_bf16(a, VA[((c*4+h)*4+nt)*64+lane], o_,0,0,0);
      #pragma unroll
      for(int reg=0;reg<4;reg++){
        int n2=nt*16+l15, row=lq*4+reg;
        long inst=(n0+row)*16+c;
        float val=o_[reg];
        if(n2<32)      out[inst*128 + h*32+n2]=val;
        else if(n2<56) outv[inst*96 + h*24 + n2-32]=val;
      }
    }
  }
}

extern "C" void kernel_launch(void* const* d_in, const int* in_sizes, int n_in,
                              void* d_out, int out_size, void* d_ws, size_t ws_size,
                              hipStream_t stream){
  (void)in_sizes; (void)n_in; (void)out_size; (void)ws_size;
  const float* s = (const float*)d_in[0];
  const float* v = (const float*)d_in[1];
  float* wsf = (float*)d_ws;
  float* out = (float*)d_out;
  ushort_t* qatt  = (ushort_t*)d_out;
  ushort_t* vh_s  = (ushort_t*)((char*)d_out + VH_B);
  ushort_t* avn_s = (ushort_t*)((char*)d_out + AVN_B);
  (void)hipMemsetAsync((char*)d_ws + OFF_SGL*sizeof(float), 0, (size_t)(65536+49152)*sizeof(float), stream);
  k0_prep<<<13,256,0,stream>>>(
      (const float*)d_in[2],(const float*)d_in[3],
      (const float*)d_in[5],(const float*)d_in[6],(const float*)d_in[8],(const float*)d_in[9],
      (const float*)d_in[11],(const float*)d_in[12],(const float*)d_in[14],(const float*)d_in[15],
      (const float*)d_in[17],(const float*)d_in[18],(const float*)d_in[20],(const float*)d_in[21], wsf);
  kA_vn<<<1024,256,0,stream>>>(v, wsf, vh_s, avn_s);
  kB_gemm<<<2048,256,0,stream>>>(s, wsf, (const float*)d_in[7], (const float*)d_in[4],
                                 (const float*)d_in[10], qatt, vh_s, avn_s);
  k2a_stats<<<dim3(16,32),256,0,stream>>>(wsf);
  k2b_merge<<<2,256,0,stream>>>(wsf);
  k3_globals<<<512,256,0,stream>>>(s, v, wsf);
  k4_kvgvp<<<512,64,0,stream>>>(wsf, (const float*)d_in[13], (const float*)d_in[16],
                                (const float*)d_in[19], (const float*)d_in[22]);
  k5_attn<<<dim3(128,16),256,0,stream>>>(wsf, out);
}